// Round 3
// baseline (817.599 us; speedup 1.0000x reference)
//
#include <hip/hip_runtime.h>

#define NBATCH 8
#define CH 64
#define HH 256
#define WW 256

using f32x4 = __attribute__((ext_vector_type(4))) float;
using s16x8 = __attribute__((ext_vector_type(8))) short;
typedef unsigned short ushort_t;

// LDS map (35072 B -> 4 blocks/CU), phase-overlaid union:
//  [0,17408)      bigf: fp32 [64][68]  (T -> W2 -> P)  |  phase2: AvT bf16 [64][16 slots]
//  [17408,33792)  phase1: Aq bf16 [64][8 slots] + Ak bf16 [64][8 slots]
//                 phase3b/2: M bf16 [64][16 slots]
//  [33792,35072)  ssq, ssk, salpha, sbeta, spbd  (5 x 64 floats)
#define SM_BYTES 35072
#define AQ_OFF 17408
#define AK_OFF (17408 + 8192)
#define M_OFF  17408
#define VEC_OFF 33792

// Exact split: hi = bf16-truncate(x) (mantissa mask, exact), lo = x - hi (exact).
// a*b ~= ah*bh + ah*bl + al*bh  (al*bl ~ 2^-16 rel, dropped) -> fp32-grade MFMA GEMM.
__global__ __launch_bounds__(256, 2)
void fused_ca(const float* __restrict__ hid, const float* __restrict__ ctx,
              const float* __restrict__ qdw, const float* __restrict__ qdb,
              const float* __restrict__ qpw, const float* __restrict__ qpb,
              const float* __restrict__ kdw, const float* __restrict__ kdb,
              const float* __restrict__ kpw, const float* __restrict__ kpb,
              const float* __restrict__ vdw, const float* __restrict__ vdb,
              const float* __restrict__ vpw, const float* __restrict__ vpb,
              float* __restrict__ out)
{
    __shared__ alignas(16) char sm[SM_BYTES];
    float* bigf   = (float*)sm;
    float* ssq    = (float*)(sm + VEC_OFF);
    float* ssk    = ssq + 64;
    float* salpha = ssq + 128;
    float* sbeta  = ssq + 192;
    float* spbd   = ssq + 256;

    const int tid  = threadIdx.x;
    const int wid  = tid >> 6;          // wave 0..3  -> owns T/O rows [16*wid, 16*wid+16)
    const int lane = tid & 63;
    const int sl   = lane >> 4;         // k-slot selector for MFMA frags

    // XCD-aware bijective swizzle (2048 = 8 XCDs x 256)
    const int wg = (blockIdx.x & 7) * ((int)gridDim.x >> 3) + ((int)blockIdx.x >> 3);
    const int b  = wg >> 8, h = wg & 255;

    const int r  = tid >> 2;            // channel / row 0..63
    const int g  = tid & 3;
    const int c0 = g * 16;              // 16-wide col base (GEMM phases, phase-2 conv)
    const float SCALE = 0.35355339059327373f;   // 1/sqrt(8)

    auto pack2 = [](float x, float y) -> unsigned int {
        return (__float_as_uint(x) >> 16) | (__float_as_uint(y) & 0xFFFF0000u);
    };

    // ---- depthwise 3x3, 8-wide strip; split-bf16 write to tile at dstoff ----
    // tile layout: [64 rows][128 B]: hi k-slots 0..3, lo k-slots 4..7, slot ^= (row&7)
    auto conv8 = [&](const float* __restrict__ src, const float* wgt, float bias,
                     int wc, int dstoff) -> float {
        float acc[8];
        #pragma unroll
        for (int i = 0; i < 8; i++) acc[i] = bias;
        const int wb = wc * 32 + g * 8;
        const float* p0 = src + ((size_t)b * CH + r) * (HH * WW) + wb;
        const int offL = (wb > 0) ? -1 : 0;
        const int offR = (wb + 8 < WW) ? 8 : 7;
        #pragma unroll
        for (int dy = 0; dy < 3; dy++) {
            const int hr = h + dy - 1;
            if (hr < 0 || hr >= HH) continue;     // uniform (h uniform per block)
            const float* p = p0 + (size_t)hr * WW;
            const float4 t0 = *(const float4*)p;
            const float4 t1 = *(const float4*)(p + 4);
            float tl = p[offL]; if (wb == 0) tl = 0.f;
            float tr = p[offR]; if (wb + 8 >= WW) tr = 0.f;
            const float t[10] = {tl, t0.x, t0.y, t0.z, t0.w, t1.x, t1.y, t1.z, t1.w, tr};
            #pragma unroll
            for (int dx = 0; dx < 3; dx++) {
                const float wv = wgt[dy * 3 + dx];
                #pragma unroll
                for (int i = 0; i < 8; i++) acc[i] += t[i + dx] * wv;
            }
        }
        float s = 0.f;
        #pragma unroll
        for (int i = 0; i < 8; i++) s += acc[i];
        float lo[8];
        #pragma unroll
        for (int i = 0; i < 8; i++) {
            const float hf = __uint_as_float(__float_as_uint(acc[i]) & 0xFFFF0000u);
            lo[i] = acc[i] - hf;
        }
        const uint4 uh = make_uint4(pack2(acc[0], acc[1]), pack2(acc[2], acc[3]),
                                    pack2(acc[4], acc[5]), pack2(acc[6], acc[7]));
        const uint4 ul = make_uint4(pack2(lo[0], lo[1]), pack2(lo[2], lo[3]),
                                    pack2(lo[4], lo[5]), pack2(lo[6], lo[7]));
        *(uint4*)(sm + dstoff + r * 128 + (((g    ) ^ (r & 7)) << 4)) = uh;
        *(uint4*)(sm + dstoff + r * 128 + (((g + 4) ^ (r & 7)) << 4)) = ul;
        return s;
    };

    // ---- hoist q/k depthwise weights ----
    float qw[9], kw[9];
    #pragma unroll
    for (int i = 0; i < 9; i++) { qw[i] = qdw[r * 9 + i]; kw[i] = kdw[r * 9 + i]; }
    const float qb = qdb[r], kb = kdb[r];

    // ================= phase 1: T = Aq*Ak^T via split-bf16 MFMA =================
    f32x4 accT[4];
    #pragma unroll
    for (int tn = 0; tn < 4; tn++) accT[tn] = f32x4{0.f, 0.f, 0.f, 0.f};
    float sq_part = 0.f, sk_part = 0.f;

    for (int wc = 0; wc < 8; wc++) {              // K-chunks of 32
        sq_part += conv8(hid, qw, qb, wc, AQ_OFF);
        sk_part += conv8(ctx, kw, kb, wc, AK_OFF);
        __syncthreads();
        const int ra = (wid << 4) + (lane & 15);
        const s16x8 ah = *(const s16x8*)(sm + AQ_OFF + ra * 128 + (((sl    ) ^ (ra & 7)) << 4));
        const s16x8 al = *(const s16x8*)(sm + AQ_OFF + ra * 128 + (((sl + 4) ^ (ra & 7)) << 4));
        #pragma unroll
        for (int tn = 0; tn < 4; tn++) {
            const int rb = (tn << 4) + (lane & 15);
            const s16x8 bh = *(const s16x8*)(sm + AK_OFF + rb * 128 + (((sl    ) ^ (rb & 7)) << 4));
            const s16x8 bl = *(const s16x8*)(sm + AK_OFF + rb * 128 + (((sl + 4) ^ (rb & 7)) << 4));
            accT[tn] = __builtin_amdgcn_mfma_f32_16x16x32_bf16(ah, bh, accT[tn], 0, 0, 0);
            accT[tn] = __builtin_amdgcn_mfma_f32_16x16x32_bf16(ah, bl, accT[tn], 0, 0, 0);
            accT[tn] = __builtin_amdgcn_mfma_f32_16x16x32_bf16(al, bh, accT[tn], 0, 0, 0);
        }
        __syncthreads();
    }

    // row sums sq, sk (4-lane group reduce)
    sq_part += __shfl_xor(sq_part, 1); sq_part += __shfl_xor(sq_part, 2);
    sk_part += __shfl_xor(sk_part, 1); sk_part += __shfl_xor(sk_part, 2);
    if (g == 0) { ssq[r] = sq_part; ssk[r] = sk_part; }

    // T writeback: D layout col=lane&15, row=(lane>>4)*4+reg
    {
        const int rowb = (wid << 4) + ((lane >> 4) << 2);
        const int cb = lane & 15;
        #pragma unroll
        for (int tn = 0; tn < 4; tn++)
            #pragma unroll
            for (int q = 0; q < 4; q++)
                bigf[(rowb + q) * 68 + tn * 16 + cb] = accT[tn][q];
    }
    __syncthreads();

    // ================= phase 3: small chain (fp32 VALU, weights from L1) ========
    // W2 = SCALE*(qpw @ T) -> regs
    float w2a[16];
    #pragma unroll
    for (int i = 0; i < 16; i++) w2a[i] = 0.f;
    #pragma unroll 4
    for (int e4 = 0; e4 < 16; e4++) {
        const float4 wq = *(const float4*)&qpw[r * 64 + e4 * 4];
        const float ws[4] = {wq.x, wq.y, wq.z, wq.w};
        #pragma unroll
        for (int j = 0; j < 4; j++)
            #pragma unroll
            for (int i = 0; i < 16; i++)
                w2a[i] += ws[j] * bigf[(e4 * 4 + j) * 68 + c0 + i];
    }
    // alpha = qpw*sq, beta = kpw*sk
    if (tid < 64) {
        float a = 0.f;
        #pragma unroll 4
        for (int e = 0; e < 64; e += 4) {
            const float4 w4 = *(const float4*)&qpw[tid * 64 + e];
            a += w4.x * ssq[e] + w4.y * ssq[e + 1] + w4.z * ssq[e + 2] + w4.w * ssq[e + 3];
        }
        salpha[tid] = a;
    } else if (tid < 128) {
        const int d = tid - 64;
        float a = 0.f;
        #pragma unroll 4
        for (int e = 0; e < 64; e += 4) {
            const float4 w4 = *(const float4*)&kpw[d * 64 + e];
            a += w4.x * ssk[e] + w4.y * ssk[e + 1] + w4.z * ssk[e + 2] + w4.w * ssk[e + 3];
        }
        sbeta[d] = a;
    }
    __syncthreads();                    // T consumed; salpha/sbeta published

    // W2 -> big (row-local to wave)
    #pragma unroll
    for (int i = 0; i < 16; i++) bigf[r * 68 + c0 + i] = w2a[i] * SCALE;

    // S = W2 @ kpw^T + rank-1 ; softmax in regs
    float p[16];
    {
        float s[16];
        #pragma unroll
        for (int i = 0; i < 16; i++) s[i] = 0.f;
        #pragma unroll 2
        for (int e4 = 0; e4 < 16; e4++) {
            const float4 w4 = *(const float4*)&bigf[r * 68 + e4 * 4];
            #pragma unroll
            for (int i = 0; i < 16; i++) {
                const float4 kv = *(const float4*)&kpw[(c0 + i) * 64 + e4 * 4];
                s[i] += w4.x * kv.x + w4.y * kv.y + w4.z * kv.z + w4.w * kv.w;
            }
        }
        const float qpbr = qpb[r];
        const float gam  = SCALE * (salpha[r] + 256.f * qpbr);
        const float qs   = SCALE * qpbr;
        #pragma unroll
        for (int i = 0; i < 16; i++)
            s[i] += gam * kpb[c0 + i] + qs * sbeta[c0 + i];
        float m = s[0];
        #pragma unroll
        for (int i = 1; i < 16; i++) m = fmaxf(m, s[i]);
        m = fmaxf(m, __shfl_xor(m, 1));
        m = fmaxf(m, __shfl_xor(m, 2));
        float sum = 0.f;
        #pragma unroll
        for (int i = 0; i < 16; i++) { s[i] = __expf(s[i] - m); sum += s[i]; }
        sum += __shfl_xor(sum, 1);
        sum += __shfl_xor(sum, 2);
        const float inv = 1.f / sum;
        #pragma unroll
        for (int i = 0; i < 16; i++) p[i] = s[i] * inv;
    }
    // P -> big (overwrite W2; both row-local to this wave)
    #pragma unroll
    for (int i = 0; i < 16; i++) bigf[r * 68 + c0 + i] = p[i];

    // M = P @ vpw ; pbd = P . vpb   (vpw/vpb from L1)
    float macc[16];
    #pragma unroll
    for (int i = 0; i < 16; i++) macc[i] = 0.f;
    float pbd = 0.f;
    #pragma unroll 2
    for (int d4 = 0; d4 < 16; d4++) {
        const float4 p4  = *(const float4*)&bigf[r * 68 + d4 * 4];
        const float4 vb4 = *(const float4*)&vpb[d4 * 4];
        pbd += p4.x * vb4.x + p4.y * vb4.y + p4.z * vb4.z + p4.w * vb4.w;
        const float ps[4] = {p4.x, p4.y, p4.z, p4.w};
        #pragma unroll
        for (int j = 0; j < 4; j++)
            #pragma unroll
            for (int i = 0; i < 16; i++)
                macc[i] += ps[j] * vpw[(d4 * 4 + j) * 64 + c0 + i];
    }
    // M split-bf16 -> [64][16 slots] (hi slots 0..7, lo 8..15, slot ^= r&15)
    {
        float lo[16];
        #pragma unroll
        for (int i = 0; i < 16; i++) {
            const float hf = __uint_as_float(__float_as_uint(macc[i]) & 0xFFFF0000u);
            lo[i] = macc[i] - hf;
        }
        const uint4 u0 = make_uint4(pack2(macc[0], macc[1]), pack2(macc[2], macc[3]),
                                    pack2(macc[4], macc[5]), pack2(macc[6], macc[7]));
        const uint4 u1 = make_uint4(pack2(macc[8], macc[9]), pack2(macc[10], macc[11]),
                                    pack2(macc[12], macc[13]), pack2(macc[14], macc[15]));
        const uint4 l0 = make_uint4(pack2(lo[0], lo[1]), pack2(lo[2], lo[3]),
                                    pack2(lo[4], lo[5]), pack2(lo[6], lo[7]));
        const uint4 l1 = make_uint4(pack2(lo[8], lo[9]), pack2(lo[10], lo[11]),
                                    pack2(lo[12], lo[13]), pack2(lo[14], lo[15]));
        *(uint4*)(sm + M_OFF + r * 256 + (((2 * g    ) ^ (r & 15)) << 4)) = u0;
        *(uint4*)(sm + M_OFF + r * 256 + (((2 * g + 1) ^ (r & 15)) << 4)) = u1;
        *(uint4*)(sm + M_OFF + r * 256 + (((8 + 2 * g) ^ (r & 15)) << 4)) = l0;
        *(uint4*)(sm + M_OFF + r * 256 + (((9 + 2 * g) ^ (r & 15)) << 4)) = l1;
    }
    if (g == 0) spbd[r] = pbd;
    __syncthreads();                    // M + spbd published; P region reusable

    // ================= phase 2: O = M @ Av + pbd via split-bf16 MFMA ============
    float vw[9];
    #pragma unroll
    for (int i = 0; i < 9; i++) vw[i] = vdw[r * 9 + i];
    const float vb_ = vdb[r];

    // hoist A-frags of M (constant across chunks) + pbd
    const int ra2 = (wid << 4) + (lane & 15);
    const s16x8 mh0 = *(const s16x8*)(sm + M_OFF + ra2 * 256 + (((sl     ) ^ (ra2 & 15)) << 4));
    const s16x8 mh1 = *(const s16x8*)(sm + M_OFF + ra2 * 256 + (((sl +  4) ^ (ra2 & 15)) << 4));
    const s16x8 ml0 = *(const s16x8*)(sm + M_OFF + ra2 * 256 + (((sl +  8) ^ (ra2 & 15)) << 4));
    const s16x8 ml1 = *(const s16x8*)(sm + M_OFF + ra2 * 256 + (((sl + 12) ^ (ra2 & 15)) << 4));
    float pbd4[4];
    {
        const int rowb = (wid << 4) + ((lane >> 4) << 2);
        #pragma unroll
        for (int q = 0; q < 4; q++) pbd4[q] = spbd[rowb + q];
    }

    for (int wc = 0; wc < 4; wc++) {            // 4 chunks of 64 output cols
        // v-dwconv 16-wide; split-bf16 transposed scatter into AvT [64 w][16 slots] @0
        {
            float acc[16];
            #pragma unroll
            for (int i = 0; i < 16; i++) acc[i] = vb_;
            const int wb = wc * 64 + c0;
            const float* p0 = ctx + ((size_t)b * CH + r) * (HH * WW) + wb;
            const int offL = (wb > 0) ? -1 : 0;
            const int offR = (wb + 16 < WW) ? 16 : 15;
            #pragma unroll
            for (int dy = 0; dy < 3; dy++) {
                const int hr = h + dy - 1;
                if (hr < 0 || hr >= HH) continue;
                const float* p = p0 + (size_t)hr * WW;
                const float4 t0 = *(const float4*)p;
                const float4 t1 = *(const float4*)(p + 4);
                const float4 t2 = *(const float4*)(p + 8);
                const float4 t3 = *(const float4*)(p + 12);
                float tl = p[offL]; if (wb == 0) tl = 0.f;
                float tr = p[offR]; if (wb + 16 >= WW) tr = 0.f;
                const float t[18] = {tl, t0.x, t0.y, t0.z, t0.w, t1.x, t1.y, t1.z, t1.w,
                                     t2.x, t2.y, t2.z, t2.w, t3.x, t3.y, t3.z, t3.w, tr};
                #pragma unroll
                for (int dx = 0; dx < 3; dx++) {
                    const float wv = vw[dy * 3 + dx];
                    #pragma unroll
                    for (int i = 0; i < 16; i++) acc[i] += t[i + dx] * wv;
                }
            }
            #pragma unroll
            for (int i = 0; i < 16; i++) {
                const int wl = c0 + i;          // local output col = AvT row
                const unsigned int hb = __float_as_uint(acc[i]) & 0xFFFF0000u;
                const float lf = acc[i] - __uint_as_float(hb);
                *(ushort_t*)(sm + wl * 256 + ((((r >> 3)    ) ^ (wl & 15)) << 4) + ((r & 7) << 1)) =
                    (ushort_t)(hb >> 16);
                *(ushort_t*)(sm + wl * 256 + (((8 + (r >> 3)) ^ (wl & 15)) << 4) + ((r & 7) << 1)) =
                    (ushort_t)(__float_as_uint(lf) >> 16);
            }
        }
        __syncthreads();
        const int rowb = (wid << 4) + ((lane >> 4) << 2);
        #pragma unroll
        for (int tn = 0; tn < 4; tn++) {
            const int rb = (tn << 4) + (lane & 15);
            const s16x8 bh0 = *(const s16x8*)(sm + rb * 256 + (((sl     ) ^ (rb & 15)) << 4));
            const s16x8 bh1 = *(const s16x8*)(sm + rb * 256 + (((sl +  4) ^ (rb & 15)) << 4));
            const s16x8 bl0 = *(const s16x8*)(sm + rb * 256 + (((sl +  8) ^ (rb & 15)) << 4));
            const s16x8 bl1 = *(const s16x8*)(sm + rb * 256 + (((sl + 12) ^ (rb & 15)) << 4));
            f32x4 a2 = {0.f, 0.f, 0.f, 0.f};
            a2 = __builtin_amdgcn_mfma_f32_16x16x32_bf16(mh0, bh0, a2, 0, 0, 0);
            a2 = __builtin_amdgcn_mfma_f32_16x16x32_bf16(mh0, bl0, a2, 0, 0, 0);
            a2 = __builtin_amdgcn_mfma_f32_16x16x32_bf16(ml0, bh0, a2, 0, 0, 0);
            a2 = __builtin_amdgcn_mfma_f32_16x16x32_bf16(mh1, bh1, a2, 0, 0, 0);
            a2 = __builtin_amdgcn_mfma_f32_16x16x32_bf16(mh1, bl1, a2, 0, 0, 0);
            a2 = __builtin_amdgcn_mfma_f32_16x16x32_bf16(ml1, bh1, a2, 0, 0, 0);
            float* po = out + (((size_t)b * CH + rowb) * HH + h) * WW + wc * 64 + tn * 16 + (lane & 15);
            #pragma unroll
            for (int q = 0; q < 4; q++)
                po[(size_t)q * HH * WW] = a2[q] + pbd4[q];
        }
        __syncthreads();
    }
}

extern "C" void kernel_launch(void* const* d_in, const int* in_sizes, int n_in,
                              void* d_out, int out_size, void* d_ws, size_t ws_size,
                              hipStream_t stream) {
    const float* hid = (const float*)d_in[0];
    const float* ctx = (const float*)d_in[1];
    const float* qdw = (const float*)d_in[2];
    const float* qdb = (const float*)d_in[3];
    const float* qpw = (const float*)d_in[4];
    const float* qpb = (const float*)d_in[5];
    const float* kdw = (const float*)d_in[6];
    const float* kdb = (const float*)d_in[7];
    const float* kpw = (const float*)d_in[8];
    const float* kpb = (const float*)d_in[9];
    const float* vdw = (const float*)d_in[10];
    const float* vdb = (const float*)d_in[11];
    const float* vpw = (const float*)d_in[12];
    const float* vpb = (const float*)d_in[13];
    float* out = (float*)d_out;

    dim3 grid(NBATCH * HH);   // 2048 blocks, one per (b, h)
    dim3 block(256);
    fused_ca<<<grid, block, 0, stream>>>(hid, ctx, qdw, qdb, qpw, qpb,
                                         kdw, kdb, kpw, kpb, vdw, vdb, vpw, vpb,
                                         out);
}